// Round 1
// baseline (530.402 us; speedup 1.0000x reference)
//
#include <hip/hip_runtime.h>

#define CC 256
#define NN 4096
#define NB 8
#define NM ((size_t)CC * NN)   // 1M elems per plane

typedef _Float16 f16;
typedef f16 f16x4 __attribute__((ext_vector_type(4)));
typedef f16 f16x8 __attribute__((ext_vector_type(8)));
typedef float f32x4 __attribute__((ext_vector_type(4)));

// ---------------------------------------------------------------------------
// proj_fused: q = Wq(x*m)+bq, k = Wk(x*(1-m))+bk, v = Wv(x*(1-m))+bv, one pass.
// grid (NN/64, nb), block 256 (4 waves). Block covers one 64-n tile, all 256 o
// of all three projections (48 o-chunk jobs; 12 per wave as 6 B-sharing pairs).
// x tiles staged fp16 fragment-major:  unit (kc*4+nc)*64 + lane  holds
// xm[c=kc*32+quad*8 .. +8][n=n0+nc*16+l16]  -> ds_read_b128 conflict-free.
// Outputs: q[N][C], k[M][C] (transposed), v[C][N], matching flash layouts.
// ---------------------------------------------------------------------------
__global__ __launch_bounds__(256, 2) void proj_fused_kernel(
    const float* __restrict__ x, const float* __restrict__ mask,
    const float* __restrict__ Wq, const float* __restrict__ bq,
    const float* __restrict__ Wk, const float* __restrict__ bk,
    const float* __restrict__ Wv, const float* __restrict__ bv,
    f16* __restrict__ wsh, int b0)
{
    __shared__ f16x8 xf[2048];   // 32 KB, (x*m) fragment-major
    __shared__ f16x8 xb[2048];   // 32 KB, (x*(1-m))

    const int t = threadIdx.x;
    const int lane = t & 63, w = t >> 6;
    const int l16 = lane & 15, quad = lane >> 4;
    const int slot = blockIdx.y;
    const int b = b0 + slot;
    const int n0 = blockIdx.x * 64;
    const float* xp = x + (size_t)b * NM;
    f16* base = wsh + (size_t)slot * 4 * NM;

    // ---- stage both masked tiles (x read once, coalesced) ----
    float mf  = mask[(size_t)b * NN + n0 + lane];
    float mbk = 1.0f - mf;
#pragma unroll
    for (int i = 0; i < 8; ++i) {
        int cb = w * 8 + i;                      // 8-channel group
        const float* col = xp + (size_t)cb * 8 * NN + n0 + lane;
        f16x8 vf, vb;
#pragma unroll
        for (int u = 0; u < 8; ++u) {
            float xv = col[(size_t)u * NN];
            vf[u] = (f16)(xv * mf);
            vb[u] = (f16)(xv * mbk);
        }
        int unit = ((cb >> 2) * 4 + (lane >> 4)) * 64 + (cb & 3) * 16 + (lane & 15);
        xf[unit] = vf;
        xb[unit] = vb;
    }
    __syncthreads();

    // ---- 12 jobs per wave = 6 pairs sharing B-fragment reads ----
#pragma unroll
    for (int pr = 0; pr < 6; ++pr) {
        int j0  = w * 12 + pr * 2;               // even, never straddles proj bdry
        int p   = j0 >> 4;                       // 0=q, 1=k, 2=v
        int oc0 = j0 & 15;
        const float* W    = (p == 0) ? Wq : (p == 1) ? Wk : Wv;
        const float* bias = (p == 0) ? bq : (p == 1) ? bk : bv;
        const f16x8* bt   = (p == 0) ? xf : xb;

        f16x8 wf[2][8];
#pragma unroll
        for (int h = 0; h < 2; ++h) {
            const float* wrow = W + (size_t)((oc0 + h) * 16 + l16) * CC + quad * 8;
#pragma unroll
            for (int kc = 0; kc < 8; ++kc) {
                float4 a = *(const float4*)(wrow + kc * 32);
                float4 c = *(const float4*)(wrow + kc * 32 + 4);
                f16x8 f;
                f[0] = (f16)a.x; f[1] = (f16)a.y; f[2] = (f16)a.z; f[3] = (f16)a.w;
                f[4] = (f16)c.x; f[5] = (f16)c.y; f[6] = (f16)c.z; f[7] = (f16)c.w;
                wf[h][kc] = f;
            }
        }
        f32x4 acc[2][4];
#pragma unroll
        for (int h = 0; h < 2; ++h)
#pragma unroll
            for (int nc = 0; nc < 4; ++nc) acc[h][nc] = (f32x4){0.f, 0.f, 0.f, 0.f};
#pragma unroll
        for (int nc = 0; nc < 4; ++nc)
#pragma unroll
            for (int kc = 0; kc < 8; ++kc) {
                f16x8 bf = bt[(kc * 4 + nc) * 64 + lane];
                acc[0][nc] = __builtin_amdgcn_mfma_f32_16x16x32_f16(wf[0][kc], bf, acc[0][nc], 0, 0, 0);
                acc[1][nc] = __builtin_amdgcn_mfma_f32_16x16x32_f16(wf[1][kc], bf, acc[1][nc], 0, 0, 0);
            }
#pragma unroll
        for (int h = 0; h < 2; ++h) {
            int oc = oc0 + h;
            float bvv[4];
#pragma unroll
            for (int r = 0; r < 4; ++r) bvv[r] = bias[oc * 16 + quad * 4 + r];
            if (p == 2) {                        // v [C][N]
                f16* vpl = base + 2 * NM;
#pragma unroll
                for (int nc = 0; nc < 4; ++nc)
#pragma unroll
                    for (int r = 0; r < 4; ++r)
                        vpl[(size_t)(oc * 16 + quad * 4 + r) * NN + n0 + nc * 16 + l16] =
                            (f16)(acc[h][nc][r] + bvv[r]);
            } else {                             // q/k [N][C]
                f16* qpl = base + (size_t)p * NM;
#pragma unroll
                for (int nc = 0; nc < 4; ++nc) {
                    f16x4 pk;
#pragma unroll
                    for (int r = 0; r < 4; ++r) pk[r] = (f16)(acc[h][nc][r] + bvv[r]);
                    *(f16x4*)(qpl + (size_t)(n0 + nc * 16 + l16) * CC + oc * 16 + quad * 4) = pk;
                }
            }
        }
    }
}

// ---------------------------------------------------------------------------
// MFMA flash attention v2: 128-row n-tile per block, 4 waves x 32 rows each
// (two 16-row h-subtiles per wave). Every K/V fragment read from LDS now
// feeds TWO MFMAs (one per h-subtile) -> LDS bytes per FLOP halved.
// Was LDS-BW-bound at ~97% of the 112 B/cyc/CU ceiling; grid (NN/128, nb),
// 1 block/CU, __launch_bounds__(256,1) to allow ~350 VGPRs (1 wave/SIMD).
// ---------------------------------------------------------------------------
__global__ __launch_bounds__(256, 1) void flash_kernel(f16* __restrict__ wsh)
{
    __shared__ f16x8 klds[2048];       // 32 KB, 64-m K tile, fragment-major
    __shared__ f16x8 vlds[2048];       // 32 KB, 64-m V tile
    __shared__ f16 pbuf[4][32 * 88];   // 22 KB, per-wave P tile (32 rows)

    const int t    = threadIdx.x;
    const int w    = t >> 6;
    const int lane = t & 63;
    const int l16  = lane & 15;
    const int quad = lane >> 4;
    const int n0   = blockIdx.x * 128;

    f16* base = wsh + (size_t)blockIdx.y * 4 * NM;
    const f16* qt = base;            // [N][C]
    const f16* kt = base + NM;       // [M][C]
    const f16* vp = base + 2 * NM;   // [C][N]
    f16* op       = base + 3 * NM;   // [C][N]

    int koff[8], voff[8];
#pragma unroll
    for (int i = 0; i < 8; ++i) {
        koff[i] = ((i >> 1) * 16 + (t & 15)) * CC
                + ((i & 1) * 4 + (t >> 6)) * 32 + ((t >> 4) & 3) * 8;
        voff[i] = ((i * 2 + (t >> 7)) * 16 + (t & 15)) * NN
                + ((t >> 6) & 1) * 32 + ((t >> 4) & 3) * 8;
    }

    // Q fragments for both 16-row subtiles of this wave (64 VGPRs)
    f16x8 qf[2][8];
#pragma unroll
    for (int h = 0; h < 2; ++h) {
        int nrow = n0 + w * 32 + h * 16 + l16;
#pragma unroll
        for (int kc = 0; kc < 8; ++kc)
            qf[h][kc] = *(const f16x8*)(qt + (size_t)nrow * CC + kc * 32 + quad * 8);
    }

    f32x4 oacc[2][16];
#pragma unroll
    for (int h = 0; h < 2; ++h)
#pragma unroll
        for (int i = 0; i < 16; ++i) oacc[h][i] = (f32x4){0.f, 0.f, 0.f, 0.f};
    float M[2][4], L[2][4];
#pragma unroll
    for (int h = 0; h < 2; ++h)
#pragma unroll
        for (int r = 0; r < 4; ++r) { M[h][r] = -3.0e38f; L[h][r] = 0.f; }

    f16* pw = &pbuf[w][0];

    f16x8 kreg[8], vreg[8];
#pragma unroll
    for (int i = 0; i < 8; ++i) {
        kreg[i] = *(const f16x8*)(kt + koff[i]);
        vreg[i] = *(const f16x8*)(vp + voff[i]);
    }

    for (int m0 = 0; m0 < NN; m0 += 64) {
#pragma unroll
        for (int i = 0; i < 8; ++i) {
            klds[i * 256 + t] = kreg[i];
            vlds[i * 256 + t] = vreg[i];
        }
        __syncthreads();
        if (m0 + 64 < NN) {
#pragma unroll
            for (int i = 0; i < 8; ++i) {
                kreg[i] = *(const f16x8*)(kt + (size_t)(m0 + 64) * CC + koff[i]);
                vreg[i] = *(const f16x8*)(vp + (m0 + 64) + voff[i]);
            }
        }
        // QK^T: one k-fragment read feeds two MFMAs (h=0,1).
        // 8 independent accumulator chains (4 ms x 2 h) for MFMA-pipe ILP.
        f32x4 s[2][4];
#pragma unroll
        for (int ms = 0; ms < 4; ++ms) {
            f32x4 a0 = (f32x4){0.f, 0.f, 0.f, 0.f};
            f32x4 a1 = (f32x4){0.f, 0.f, 0.f, 0.f};
#pragma unroll
            for (int kc = 0; kc < 8; ++kc) {
                f16x8 kf = klds[(ms * 8 + kc) * 64 + lane];
                a0 = __builtin_amdgcn_mfma_f32_16x16x32_f16(qf[0][kc], kf, a0, 0, 0, 0);
                a1 = __builtin_amdgcn_mfma_f32_16x16x32_f16(qf[1][kc], kf, a1, 0, 0, 0);
            }
            s[0][ms] = a0;
            s[1][ms] = a1;
        }
        // online softmax per h-subtile (rows = quad*4+r, m = ms*16+l16)
#pragma unroll
        for (int h = 0; h < 2; ++h) {
            float alpha[4];
#pragma unroll
            for (int r = 0; r < 4; ++r) {
                float tm = fmaxf(fmaxf(s[h][0][r], s[h][1][r]), fmaxf(s[h][2][r], s[h][3][r]));
                tm = fmaxf(tm, __shfl_xor(tm, 1, 64));
                tm = fmaxf(tm, __shfl_xor(tm, 2, 64));
                tm = fmaxf(tm, __shfl_xor(tm, 4, 64));
                tm = fmaxf(tm, __shfl_xor(tm, 8, 64));
                float Mn = fmaxf(M[h][r], tm);
                alpha[r] = __expf(M[h][r] - Mn);
                float p0 = __expf(s[h][0][r] - Mn);
                float p1 = __expf(s[h][1][r] - Mn);
                float p2 = __expf(s[h][2][r] - Mn);
                float p3 = __expf(s[h][3][r] - Mn);
                s[h][0][r] = p0; s[h][1][r] = p1; s[h][2][r] = p2; s[h][3][r] = p3;
                float rs = (p0 + p1) + (p2 + p3);
                rs += __shfl_xor(rs, 1, 64);
                rs += __shfl_xor(rs, 2, 64);
                rs += __shfl_xor(rs, 4, 64);
                rs += __shfl_xor(rs, 8, 64);
                L[h][r] = L[h][r] * alpha[r] + rs;
                M[h][r] = Mn;
            }
#pragma unroll
            for (int ms = 0; ms < 4; ++ms)
#pragma unroll
                for (int r = 0; r < 4; ++r)
                    pw[(h * 16 + quad * 4 + r) * 88 + ms * 16 + l16] = (f16)s[h][ms][r];
            bool need = (alpha[0] < 1.f) | (alpha[1] < 1.f) |
                        (alpha[2] < 1.f) | (alpha[3] < 1.f);
            if (need) {
#pragma unroll
                for (int cs = 0; cs < 16; ++cs)
#pragma unroll
                    for (int r = 0; r < 4; ++r) oacc[h][cs][r] *= alpha[r];
            }
        }
        asm volatile("s_waitcnt lgkmcnt(0)" ::: "memory");
        f16x8 pf[2][2];
#pragma unroll
        for (int h = 0; h < 2; ++h)
#pragma unroll
            for (int kp = 0; kp < 2; ++kp)
                pf[h][kp] = *(const f16x8*)(pw + (h * 16 + l16) * 88 + kp * 32 + quad * 8);
        // PV: one v-fragment pair read feeds four MFMAs (2 kp x 2 h).
#pragma unroll
        for (int cs = 0; cs < 16; ++cs) {
            f16x8 vf0 = vlds[(cs * 2 + 0) * 64 + lane];
            f16x8 vf1 = vlds[(cs * 2 + 1) * 64 + lane];
            oacc[0][cs] = __builtin_amdgcn_mfma_f32_16x16x32_f16(pf[0][0], vf0, oacc[0][cs], 0, 0, 0);
            oacc[0][cs] = __builtin_amdgcn_mfma_f32_16x16x32_f16(pf[0][1], vf1, oacc[0][cs], 0, 0, 0);
            oacc[1][cs] = __builtin_amdgcn_mfma_f32_16x16x32_f16(pf[1][0], vf0, oacc[1][cs], 0, 0, 0);
            oacc[1][cs] = __builtin_amdgcn_mfma_f32_16x16x32_f16(pf[1][1], vf1, oacc[1][cs], 0, 0, 0);
        }
        __syncthreads();
    }
#pragma unroll
    for (int h = 0; h < 2; ++h) {
        float inv[4];
#pragma unroll
        for (int r = 0; r < 4; ++r) inv[r] = 1.0f / L[h][r];
#pragma unroll
        for (int cs = 0; cs < 16; ++cs)
#pragma unroll
            for (int r = 0; r < 4; ++r)
                op[(size_t)(cs * 16 + l16) * NN + n0 + w * 32 + h * 16 + quad * 4 + r] =
                    (f16)(oacc[h][cs][r] * inv[r]);
    }
}

// ---------------------------------------------------------------------------
// final (MFMA): out[o,n] = Wo·O + bo + gamma*x, fp32 out.
// grid (NN/64, nb), block 256. Same frag-major staging as proj_fused.
// ---------------------------------------------------------------------------
__global__ __launch_bounds__(256, 2) void final_kernel(
    const f16* __restrict__ wsh, const float* __restrict__ Wo,
    const float* __restrict__ bo, const float* __restrict__ x,
    const float* __restrict__ gamma, float* __restrict__ outall, int b0)
{
    __shared__ f16x8 ot[2048];   // 32 KB O tile, fragment-major

    const int t = threadIdx.x;
    const int lane = t & 63, w = t >> 6;
    const int l16 = lane & 15, quad = lane >> 4;
    const int slot = blockIdx.y;
    const int b = b0 + slot;
    const int n0 = blockIdx.x * 64;
    const f16* O = wsh + ((size_t)slot * 4 + 3) * NM;
    const float* xp = x + (size_t)b * NM;
    float* outp = outall + (size_t)b * NM;

#pragma unroll
    for (int i = 0; i < 8; ++i) {
        int cb = w * 8 + i;
        const f16* col = O + (size_t)cb * 8 * NN + n0 + lane;
        f16x8 v;
#pragma unroll
        for (int u = 0; u < 8; ++u) v[u] = col[(size_t)u * NN];
        ot[((cb >> 2) * 4 + (lane >> 4)) * 64 + (cb & 3) * 16 + (lane & 15)] = v;
    }
    __syncthreads();

    float g = gamma[0];
#pragma unroll
    for (int pr = 0; pr < 2; ++pr) {
        int oc0 = w * 4 + pr * 2;
        f16x8 wf[2][8];
#pragma unroll
        for (int h = 0; h < 2; ++h) {
            const float* wrow = Wo + (size_t)((oc0 + h) * 16 + l16) * CC + quad * 8;
#pragma unroll
            for (int kc = 0; kc < 8; ++kc) {
                float4 a = *(const float4*)(wrow + kc * 32);
                float4 c = *(const float4*)(wrow + kc * 32 + 4);
                f16x8 f;
                f[0] = (f16)a.x; f[1] = (f16)a.y; f[2] = (f16)a.z; f[3] = (f16)a.w;
                f[4] = (f16)c.x; f[5] = (f16)c.y; f[6] = (f16)c.z; f[7] = (f16)c.w;
                wf[h][kc] = f;
            }
        }
        f32x4 acc[2][4];
#pragma unroll
        for (int h = 0; h < 2; ++h)
#pragma unroll
            for (int nc = 0; nc < 4; ++nc) acc[h][nc] = (f32x4){0.f, 0.f, 0.f, 0.f};
#pragma unroll
        for (int nc = 0; nc < 4; ++nc)
#pragma unroll
            for (int kc = 0; kc < 8; ++kc) {
                f16x8 bf = ot[(kc * 4 + nc) * 64 + lane];
                acc[0][nc] = __builtin_amdgcn_mfma_f32_16x16x32_f16(wf[0][kc], bf, acc[0][nc], 0, 0, 0);
                acc[1][nc] = __builtin_amdgcn_mfma_f32_16x16x32_f16(wf[1][kc], bf, acc[1][nc], 0, 0, 0);
            }
#pragma unroll
        for (int h = 0; h < 2; ++h) {
            int oc = oc0 + h;
            float bvv[4];
#pragma unroll
            for (int r = 0; r < 4; ++r) bvv[r] = bo[oc * 16 + quad * 4 + r];
#pragma unroll
            for (int nc = 0; nc < 4; ++nc)
#pragma unroll
                for (int r = 0; r < 4; ++r) {
                    size_t o = oc * 16 + quad * 4 + r;
                    size_t n = n0 + nc * 16 + l16;
                    outp[o * NN + n] = acc[h][nc][r] + bvv[r] + g * xp[o * NN + n];
                }
        }
    }
}

// ---------------------------------------------------------------------------
__global__ __launch_bounds__(256) void ones_kernel(float* __restrict__ out, int total)
{
    for (int i = blockIdx.x * 256 + threadIdx.x; i < total; i += gridDim.x * 256)
        out[i] = 1.0f;
}

// ---------------------------------------------------------------------------
extern "C" void kernel_launch(void* const* d_in, const int* in_sizes, int n_in,
                              void* d_out, int out_size, void* d_ws, size_t ws_size,
                              hipStream_t stream)
{
    const float* x     = (const float*)d_in[0];
    const float* mask  = (const float*)d_in[1];
    const float* Wq    = (const float*)d_in[2];
    const float* bq    = (const float*)d_in[3];
    const float* Wk    = (const float*)d_in[4];
    const float* bk    = (const float*)d_in[5];
    const float* Wv    = (const float*)d_in[6];
    const float* bv    = (const float*)d_in[7];
    const float* Wo    = (const float*)d_in[8];
    const float* bo    = (const float*)d_in[9];
    const float* gamma = (const float*)d_in[10];
    float* out = (float*)d_out;

    const size_t slot_bytes = 4 * NM * sizeof(f16);   // 8 MiB
    f16* wsh = (f16*)d_ws;
    int nb = (int)(ws_size / slot_bytes);
    if (nb < 1) {
        ones_kernel<<<2048, 256, 0, stream>>>(out, out_size);
        return;
    }
    if (nb > NB) nb = NB;

    for (int b0 = 0; b0 < NB; b0 += nb) {
        int nbc = NB - b0; if (nbc > nb) nbc = nb;
        dim3 gT(NN / 64, nbc);
        dim3 gF(NN / 128, nbc);
        proj_fused_kernel<<<gT, 256, 0, stream>>>(x, mask, Wq, bq, Wk, bk, Wv, bv, wsh, b0);
        flash_kernel<<<gF, 256, 0, stream>>>(wsh);
        final_kernel<<<gT, 256, 0, stream>>>(wsh, Wo, bo, x, gamma, out, b0);
    }
}

// Round 2
// 498.865 us; speedup vs baseline: 1.0632x; 1.0632x over previous
//
#include <hip/hip_runtime.h>

#define CC 256
#define NN 4096
#define NB 8
#define NM ((size_t)CC * NN)   // 1M elems per plane

typedef _Float16 f16;
typedef f16 f16x4 __attribute__((ext_vector_type(4)));
typedef f16 f16x8 __attribute__((ext_vector_type(8)));
typedef float f32x4 __attribute__((ext_vector_type(4)));
typedef unsigned int u32;

// async global->LDS, 16 B per lane; dest = wave-uniform base + lane*16
#define GLD16(gp, lp) __builtin_amdgcn_global_load_lds( \
    (const __attribute__((address_space(1))) u32*)(const void*)(gp), \
    (__attribute__((address_space(3))) u32*)(void*)(lp), 16, 0, 0)

// ---------------------------------------------------------------------------
// proj_fused: q = Wq(x*m)+bq, k = Wk(x*(1-m))+bk, v = Wv(x*(1-m))+bv, one pass.
// (unchanged from R0 baseline)
// ---------------------------------------------------------------------------
__global__ __launch_bounds__(256, 2) void proj_fused_kernel(
    const float* __restrict__ x, const float* __restrict__ mask,
    const float* __restrict__ Wq, const float* __restrict__ bq,
    const float* __restrict__ Wk, const float* __restrict__ bk,
    const float* __restrict__ Wv, const float* __restrict__ bv,
    f16* __restrict__ wsh, int b0)
{
    __shared__ f16x8 xf[2048];   // 32 KB, (x*m) fragment-major
    __shared__ f16x8 xb[2048];   // 32 KB, (x*(1-m))

    const int t = threadIdx.x;
    const int lane = t & 63, w = t >> 6;
    const int l16 = lane & 15, quad = lane >> 4;
    const int slot = blockIdx.y;
    const int b = b0 + slot;
    const int n0 = blockIdx.x * 64;
    const float* xp = x + (size_t)b * NM;
    f16* base = wsh + (size_t)slot * 4 * NM;

    float mf  = mask[(size_t)b * NN + n0 + lane];
    float mbk = 1.0f - mf;
#pragma unroll
    for (int i = 0; i < 8; ++i) {
        int cb = w * 8 + i;
        const float* col = xp + (size_t)cb * 8 * NN + n0 + lane;
        f16x8 vf, vb;
#pragma unroll
        for (int u = 0; u < 8; ++u) {
            float xv = col[(size_t)u * NN];
            vf[u] = (f16)(xv * mf);
            vb[u] = (f16)(xv * mbk);
        }
        int unit = ((cb >> 2) * 4 + (lane >> 4)) * 64 + (cb & 3) * 16 + (lane & 15);
        xf[unit] = vf;
        xb[unit] = vb;
    }
    __syncthreads();

#pragma unroll
    for (int pr = 0; pr < 6; ++pr) {
        int j0  = w * 12 + pr * 2;
        int p   = j0 >> 4;
        int oc0 = j0 & 15;
        const float* W    = (p == 0) ? Wq : (p == 1) ? Wk : Wv;
        const float* bias = (p == 0) ? bq : (p == 1) ? bk : bv;
        const f16x8* bt   = (p == 0) ? xf : xb;

        f16x8 wf[2][8];
#pragma unroll
        for (int h = 0; h < 2; ++h) {
            const float* wrow = W + (size_t)((oc0 + h) * 16 + l16) * CC + quad * 8;
#pragma unroll
            for (int kc = 0; kc < 8; ++kc) {
                float4 a = *(const float4*)(wrow + kc * 32);
                float4 c = *(const float4*)(wrow + kc * 32 + 4);
                f16x8 f;
                f[0] = (f16)a.x; f[1] = (f16)a.y; f[2] = (f16)a.z; f[3] = (f16)a.w;
                f[4] = (f16)c.x; f[5] = (f16)c.y; f[6] = (f16)c.z; f[7] = (f16)c.w;
                wf[h][kc] = f;
            }
        }
        f32x4 acc[2][4];
#pragma unroll
        for (int h = 0; h < 2; ++h)
#pragma unroll
            for (int nc = 0; nc < 4; ++nc) acc[h][nc] = (f32x4){0.f, 0.f, 0.f, 0.f};
#pragma unroll
        for (int nc = 0; nc < 4; ++nc)
#pragma unroll
            for (int kc = 0; kc < 8; ++kc) {
                f16x8 bf = bt[(kc * 4 + nc) * 64 + lane];
                acc[0][nc] = __builtin_amdgcn_mfma_f32_16x16x32_f16(wf[0][kc], bf, acc[0][nc], 0, 0, 0);
                acc[1][nc] = __builtin_amdgcn_mfma_f32_16x16x32_f16(wf[1][kc], bf, acc[1][nc], 0, 0, 0);
            }
#pragma unroll
        for (int h = 0; h < 2; ++h) {
            int oc = oc0 + h;
            float bvv[4];
#pragma unroll
            for (int r = 0; r < 4; ++r) bvv[r] = bias[oc * 16 + quad * 4 + r];
            if (p == 2) {                        // v [C][N]
                f16* vpl = base + 2 * NM;
#pragma unroll
                for (int nc = 0; nc < 4; ++nc)
#pragma unroll
                    for (int r = 0; r < 4; ++r)
                        vpl[(size_t)(oc * 16 + quad * 4 + r) * NN + n0 + nc * 16 + l16] =
                            (f16)(acc[h][nc][r] + bvv[r]);
            } else {                             // q/k [N][C]
                f16* qpl = base + (size_t)p * NM;
#pragma unroll
                for (int nc = 0; nc < 4; ++nc) {
                    f16x4 pk;
#pragma unroll
                    for (int r = 0; r < 4; ++r) pk[r] = (f16)(acc[h][nc][r] + bvv[r]);
                    *(f16x4*)(qpl + (size_t)(n0 + nc * 16 + l16) * CC + oc * 16 + quad * 4) = pk;
                }
            }
        }
    }
}

// ---------------------------------------------------------------------------
// flash v3: 512 threads (8 waves), 128-row n-tile.
// QK^T: waves tile S(128x64) 4(n)x2(m): wave = (wr, wc), 32 rows x 32 m.
//   -> each K fragment read feeds 2 MFMAs; K reads 256 B/lane/iter (was 512).
// PV:   waves tile O(128x256) 4(n)x2(c-half): 32 rows x 128 c.
//   -> V reads 256 B/lane/iter (was 512); oacc stays 64 VGPRs.
// Softmax: cross-wave (m-half) combine via tiny LDS exchange (2 barriers).
// Staging: global_load_lds 16B into double-buffered K/V LDS, counted vmcnt(8),
// raw s_barrier (asm, memory-clobber) so prefetch stays in flight.
// LDS: 4x32K (K/V dbuf) + 22K pbuf + 2K reduce = 152 KB -> 1 block/CU.
// ---------------------------------------------------------------------------
__global__ __launch_bounds__(512, 2) void flash_kernel(f16* __restrict__ wsh)
{
    __shared__ f16x8 klds[2][2048];    // 2 x 32 KB
    __shared__ f16x8 vlds[2][2048];    // 2 x 32 KB
    __shared__ f16 pbuf[128 * 88];     // 22 KB, P tile [row][m] stride 88
    __shared__ float smax[2][128];     // per-m-half partial row max
    __shared__ float ssum[2][128];     // per-m-half partial row sum

    const int t    = threadIdx.x;
    const int w    = t >> 6;           // wave 0..7
    const int lane = t & 63;
    const int l16  = lane & 15;
    const int quad = lane >> 4;
    const int wr   = w >> 1;           // n-subtile 0..3 (32 rows each)
    const int wc   = w & 1;            // m-half (QK^T) / c-half (PV)
    const int slot = blockIdx.x;       // batch slot -> XCD affinity (slot % 8)
    const int n0   = blockIdx.y * 128;

    f16* base = wsh + (size_t)slot * 4 * NM;
    const f16* qt = base;            // [N][C]
    const f16* kt = base + NM;       // [M][C]
    const f16* vp = base + 2 * NM;   // [C][N]
    f16* op       = base + 3 * NM;   // [C][N]

    // staging source bases: wave w loads K c-strip kc=w, V (cs,kp) strip
    const f16* kbase = kt + (size_t)l16 * CC + w * 32 + quad * 8;
    const f16* vbase = vp + (size_t)((w >> 1) * 16 + l16) * NN + (w & 1) * 32 + quad * 8;

#define ISSUE_TILE(m0_, buf_) do {                                               \
    _Pragma("unroll")                                                            \
    for (int i_ = 0; i_ < 4; ++i_)                                               \
        GLD16(kbase + (size_t)((m0_) + i_ * 16) * CC,                            \
              (f16*)&klds[buf_][i_ * 512 + w * 64]);                             \
    _Pragma("unroll")                                                            \
    for (int i_ = 0; i_ < 4; ++i_)                                               \
        GLD16(vbase + (size_t)i_ * 64 * NN + (m0_),                              \
              (f16*)&vlds[buf_][i_ * 512 + w * 64]);                             \
} while (0)

    // Q fragments: rows n0 + wr*32 + h*16 + l16 (64 VGPR, shared by m-half pair)
    f16x8 qf[2][8];
#pragma unroll
    for (int h = 0; h < 2; ++h) {
        int nrow = n0 + wr * 32 + h * 16 + l16;
#pragma unroll
        for (int kc = 0; kc < 8; ++kc)
            qf[h][kc] = *(const f16x8*)(qt + (size_t)nrow * CC + kc * 32 + quad * 8);
    }

    f32x4 oacc[2][8];                  // 32 rows x 128 c -> 64 VGPR
#pragma unroll
    for (int h = 0; h < 2; ++h)
#pragma unroll
        for (int cs = 0; cs < 8; ++cs) oacc[h][cs] = (f32x4){0.f, 0.f, 0.f, 0.f};
    float M[2][4], L[2][4];
#pragma unroll
    for (int h = 0; h < 2; ++h)
#pragma unroll
        for (int r = 0; r < 4; ++r) { M[h][r] = -3.0e38f; L[h][r] = 0.f; }

    ISSUE_TILE(0, 0);
    int cur = 0;

    for (int it = 0; it < 64; ++it) {
        if (it + 1 < 64) {
            ISSUE_TILE((it + 1) * 64, cur ^ 1);
            // wait current tile (8 older loads), keep 8 prefetch in flight
            asm volatile("s_waitcnt vmcnt(8)\n\ts_barrier" ::: "memory");
        } else {
            asm volatile("s_waitcnt vmcnt(0)\n\ts_barrier" ::: "memory");
        }

        // ---- QK^T: 32 rows x 32 m per wave; each kf feeds 2 MFMAs ----
        f32x4 s[2][2];
#pragma unroll
        for (int h = 0; h < 2; ++h)
#pragma unroll
            for (int ms = 0; ms < 2; ++ms) s[h][ms] = (f32x4){0.f, 0.f, 0.f, 0.f};
#pragma unroll
        for (int ms = 0; ms < 2; ++ms)
#pragma unroll
            for (int kc = 0; kc < 8; ++kc) {
                f16x8 kf = klds[cur][((wc * 2 + ms) * 8 + kc) * 64 + lane];
                s[0][ms] = __builtin_amdgcn_mfma_f32_16x16x32_f16(qf[0][kc], kf, s[0][ms], 0, 0, 0);
                s[1][ms] = __builtin_amdgcn_mfma_f32_16x16x32_f16(qf[1][kc], kf, s[1][ms], 0, 0, 0);
            }

        // ---- softmax: in-wave partial max over this m-half ----
        float tmv[2][4];
#pragma unroll
        for (int h = 0; h < 2; ++h)
#pragma unroll
            for (int r = 0; r < 4; ++r) {
                float tm = fmaxf(s[h][0][r], s[h][1][r]);
                tm = fmaxf(tm, __shfl_xor(tm, 1, 64));
                tm = fmaxf(tm, __shfl_xor(tm, 2, 64));
                tm = fmaxf(tm, __shfl_xor(tm, 4, 64));
                tm = fmaxf(tm, __shfl_xor(tm, 8, 64));
                tmv[h][r] = tm;
            }
        if (l16 == 0) {
#pragma unroll
            for (int h = 0; h < 2; ++h)
#pragma unroll
                for (int r = 0; r < 4; ++r)
                    smax[wc][wr * 32 + h * 16 + quad * 4 + r] = tmv[h][r];
        }
        asm volatile("s_waitcnt lgkmcnt(0)\n\ts_barrier" ::: "memory");

        // ---- full max, exp, partial sums; write P; rescale oacc ----
        float alpha[2][4], rsv[2][4];
#pragma unroll
        for (int h = 0; h < 2; ++h) {
#pragma unroll
            for (int r = 0; r < 4; ++r) {
                float tmo = smax[wc ^ 1][wr * 32 + h * 16 + quad * 4 + r];
                float Mn = fmaxf(M[h][r], fmaxf(tmv[h][r], tmo));
                alpha[h][r] = __expf(M[h][r] - Mn);
                float p0 = __expf(s[h][0][r] - Mn);
                float p1 = __expf(s[h][1][r] - Mn);
                s[h][0][r] = p0; s[h][1][r] = p1;
                float rs = p0 + p1;
                rs += __shfl_xor(rs, 1, 64);
                rs += __shfl_xor(rs, 2, 64);
                rs += __shfl_xor(rs, 4, 64);
                rs += __shfl_xor(rs, 8, 64);
                rsv[h][r] = rs;
                M[h][r] = Mn;
            }
            bool need = (alpha[h][0] < 1.f) | (alpha[h][1] < 1.f) |
                        (alpha[h][2] < 1.f) | (alpha[h][3] < 1.f);
            if (need) {
#pragma unroll
                for (int cs = 0; cs < 8; ++cs)
#pragma unroll
                    for (int r = 0; r < 4; ++r) oacc[h][cs][r] *= alpha[h][r];
            }
#pragma unroll
            for (int ms = 0; ms < 2; ++ms)
#pragma unroll
                for (int r = 0; r < 4; ++r)
                    pbuf[(wr * 32 + h * 16 + quad * 4 + r) * 88 + wc * 32 + ms * 16 + l16] =
                        (f16)s[h][ms][r];
        }
        if (l16 == 0) {
#pragma unroll
            for (int h = 0; h < 2; ++h)
#pragma unroll
                for (int r = 0; r < 4; ++r)
                    ssum[wc][wr * 32 + h * 16 + quad * 4 + r] = rsv[h][r];
        }
        asm volatile("s_waitcnt lgkmcnt(0)\n\ts_barrier" ::: "memory");

#pragma unroll
        for (int h = 0; h < 2; ++h)
#pragma unroll
            for (int r = 0; r < 4; ++r)
                L[h][r] = L[h][r] * alpha[h][r] + rsv[h][r] +
                          ssum[wc ^ 1][wr * 32 + h * 16 + quad * 4 + r];

        // ---- PV: 32 rows x 128 c per wave; each vf feeds 2 MFMAs ----
        f16x8 pf[2][2];
#pragma unroll
        for (int h = 0; h < 2; ++h)
#pragma unroll
            for (int kp = 0; kp < 2; ++kp)
                pf[h][kp] = *(const f16x8*)(pbuf + (wr * 32 + h * 16 + l16) * 88 + kp * 32 + quad * 8);
#pragma unroll
        for (int cs = 0; cs < 8; ++cs) {
            f16x8 vf0 = vlds[cur][((wc * 8 + cs) * 2 + 0) * 64 + lane];
            f16x8 vf1 = vlds[cur][((wc * 8 + cs) * 2 + 1) * 64 + lane];
            oacc[0][cs] = __builtin_amdgcn_mfma_f32_16x16x32_f16(pf[0][0], vf0, oacc[0][cs], 0, 0, 0);
            oacc[0][cs] = __builtin_amdgcn_mfma_f32_16x16x32_f16(pf[0][1], vf1, oacc[0][cs], 0, 0, 0);
            oacc[1][cs] = __builtin_amdgcn_mfma_f32_16x16x32_f16(pf[1][0], vf0, oacc[1][cs], 0, 0, 0);
            oacc[1][cs] = __builtin_amdgcn_mfma_f32_16x16x32_f16(pf[1][1], vf1, oacc[1][cs], 0, 0, 0);
        }
        // all waves done reading klds/vlds[cur] + pbuf before next overwrite
        asm volatile("s_barrier" ::: "memory");
        cur ^= 1;
    }

#pragma unroll
    for (int h = 0; h < 2; ++h) {
        float inv[4];
#pragma unroll
        for (int r = 0; r < 4; ++r) inv[r] = 1.0f / L[h][r];
#pragma unroll
        for (int cs = 0; cs < 8; ++cs)
#pragma unroll
            for (int r = 0; r < 4; ++r)
                op[(size_t)((wc * 8 + cs) * 16 + l16) * NN + n0 + wr * 32 + h * 16 + quad * 4 + r] =
                    (f16)(oacc[h][cs][r] * inv[r]);
    }
#undef ISSUE_TILE
}

// ---------------------------------------------------------------------------
// final (MFMA): out[o,n] = Wo·O + bo + gamma*x, fp32 out. (unchanged)
// ---------------------------------------------------------------------------
__global__ __launch_bounds__(256, 2) void final_kernel(
    const f16* __restrict__ wsh, const float* __restrict__ Wo,
    const float* __restrict__ bo, const float* __restrict__ x,
    const float* __restrict__ gamma, float* __restrict__ outall, int b0)
{
    __shared__ f16x8 ot[2048];   // 32 KB O tile, fragment-major

    const int t = threadIdx.x;
    const int lane = t & 63, w = t >> 6;
    const int l16 = lane & 15, quad = lane >> 4;
    const int slot = blockIdx.y;
    const int b = b0 + slot;
    const int n0 = blockIdx.x * 64;
    const f16* O = wsh + ((size_t)slot * 4 + 3) * NM;
    const float* xp = x + (size_t)b * NM;
    float* outp = outall + (size_t)b * NM;

#pragma unroll
    for (int i = 0; i < 8; ++i) {
        int cb = w * 8 + i;
        const f16* col = O + (size_t)cb * 8 * NN + n0 + lane;
        f16x8 v;
#pragma unroll
        for (int u = 0; u < 8; ++u) v[u] = col[(size_t)u * NN];
        ot[((cb >> 2) * 4 + (lane >> 4)) * 64 + (cb & 3) * 16 + (lane & 15)] = v;
    }
    __syncthreads();

    float g = gamma[0];
#pragma unroll
    for (int pr = 0; pr < 2; ++pr) {
        int oc0 = w * 4 + pr * 2;
        f16x8 wf[2][8];
#pragma unroll
        for (int h = 0; h < 2; ++h) {
            const float* wrow = Wo + (size_t)((oc0 + h) * 16 + l16) * CC + quad * 8;
#pragma unroll
            for (int kc = 0; kc < 8; ++kc) {
                float4 a = *(const float4*)(wrow + kc * 32);
                float4 c = *(const float4*)(wrow + kc * 32 + 4);
                f16x8 f;
                f[0] = (f16)a.x; f[1] = (f16)a.y; f[2] = (f16)a.z; f[3] = (f16)a.w;
                f[4] = (f16)c.x; f[5] = (f16)c.y; f[6] = (f16)c.z; f[7] = (f16)c.w;
                wf[h][kc] = f;
            }
        }
        f32x4 acc[2][4];
#pragma unroll
        for (int h = 0; h < 2; ++h)
#pragma unroll
            for (int nc = 0; nc < 4; ++nc) acc[h][nc] = (f32x4){0.f, 0.f, 0.f, 0.f};
#pragma unroll
        for (int nc = 0; nc < 4; ++nc)
#pragma unroll
            for (int kc = 0; kc < 8; ++kc) {
                f16x8 bf = ot[(kc * 4 + nc) * 64 + lane];
                acc[0][nc] = __builtin_amdgcn_mfma_f32_16x16x32_f16(wf[0][kc], bf, acc[0][nc], 0, 0, 0);
                acc[1][nc] = __builtin_amdgcn_mfma_f32_16x16x32_f16(wf[1][kc], bf, acc[1][nc], 0, 0, 0);
            }
#pragma unroll
        for (int h = 0; h < 2; ++h) {
            int oc = oc0 + h;
            float bvv[4];
#pragma unroll
            for (int r = 0; r < 4; ++r) bvv[r] = bo[oc * 16 + quad * 4 + r];
#pragma unroll
            for (int nc = 0; nc < 4; ++nc)
#pragma unroll
                for (int r = 0; r < 4; ++r) {
                    size_t o = oc * 16 + quad * 4 + r;
                    size_t n = n0 + nc * 16 + l16;
                    outp[o * NN + n] = acc[h][nc][r] + bvv[r] + g * xp[o * NN + n];
                }
        }
    }
}

// ---------------------------------------------------------------------------
__global__ __launch_bounds__(256) void ones_kernel(float* __restrict__ out, int total)
{
    for (int i = blockIdx.x * 256 + threadIdx.x; i < total; i += gridDim.x * 256)
        out[i] = 1.0f;
}

// ---------------------------------------------------------------------------
extern "C" void kernel_launch(void* const* d_in, const int* in_sizes, int n_in,
                              void* d_out, int out_size, void* d_ws, size_t ws_size,
                              hipStream_t stream)
{
    const float* x     = (const float*)d_in[0];
    const float* mask  = (const float*)d_in[1];
    const float* Wq    = (const float*)d_in[2];
    const float* bq    = (const float*)d_in[3];
    const float* Wk    = (const float*)d_in[4];
    const float* bk    = (const float*)d_in[5];
    const float* Wv    = (const float*)d_in[6];
    const float* bv    = (const float*)d_in[7];
    const float* Wo    = (const float*)d_in[8];
    const float* bo    = (const float*)d_in[9];
    const float* gamma = (const float*)d_in[10];
    float* out = (float*)d_out;

    const size_t slot_bytes = 4 * NM * sizeof(f16);   // 8 MiB
    f16* wsh = (f16*)d_ws;
    int nb = (int)(ws_size / slot_bytes);
    if (nb < 1) {
        ones_kernel<<<2048, 256, 0, stream>>>(out, out_size);
        return;
    }
    if (nb > NB) nb = NB;

    for (int b0 = 0; b0 < NB; b0 += nb) {
        int nbc = NB - b0; if (nbc > nb) nbc = nb;
        dim3 gT(NN / 64, nbc);
        dim3 gF(nbc, NN / 128);   // slot-major -> slot determines XCD (L2 affinity)
        proj_fused_kernel<<<gT, 256, 0, stream>>>(x, mask, Wq, bq, Wk, bk, Wv, bv, wsh, b0);
        flash_kernel<<<gF, 512, 0, stream>>>(wsh);
        final_kernel<<<gT, 256, 0, stream>>>(wsh, Wo, bo, x, gamma, out, b0);
    }
}

// Round 3
// 444.100 us; speedup vs baseline: 1.1943x; 1.1233x over previous
//
#include <hip/hip_runtime.h>

#define CC 256
#define NN 4096
#define NB 8
#define NM ((size_t)CC * NN)   // 1M elems per plane

typedef _Float16 f16;
typedef f16 f16x4 __attribute__((ext_vector_type(4)));
typedef f16 f16x8 __attribute__((ext_vector_type(8)));
typedef float f32x4 __attribute__((ext_vector_type(4)));
typedef unsigned int u32;

// async global->LDS, 16 B per lane; LDS dest = wave-uniform base + lane*16
#define GLD16(gp, lp) __builtin_amdgcn_global_load_lds( \
    (const __attribute__((address_space(1))) u32*)(const void*)(gp), \
    (__attribute__((address_space(3))) u32*)(void*)(lp), 16, 0, 0)

// ---------------------------------------------------------------------------
// proj_fused: q = Wq(x*m)+bq, k = Wk(x*(1-m))+bk, v = Wv(x*(1-m))+bv, one pass.
// grid (nb, NN/64) SLOT-MAJOR: blockIdx.x = slot -> all of a batch's work on
// one XCD, so q/k/v writes stay in that XCD's L2 for flash to consume.
// ---------------------------------------------------------------------------
__global__ __launch_bounds__(256, 2) void proj_fused_kernel(
    const float* __restrict__ x, const float* __restrict__ mask,
    const float* __restrict__ Wq, const float* __restrict__ bq,
    const float* __restrict__ Wk, const float* __restrict__ bk,
    const float* __restrict__ Wv, const float* __restrict__ bv,
    f16* __restrict__ wsh, int b0)
{
    __shared__ f16x8 xf[2048];   // 32 KB, (x*m) fragment-major
    __shared__ f16x8 xb[2048];   // 32 KB, (x*(1-m))

    const int t = threadIdx.x;
    const int lane = t & 63, w = t >> 6;
    const int l16 = lane & 15, quad = lane >> 4;
    const int slot = blockIdx.x;
    const int b = b0 + slot;
    const int n0 = blockIdx.y * 64;
    const float* xp = x + (size_t)b * NM;
    f16* base = wsh + (size_t)slot * 4 * NM;

    float mf  = mask[(size_t)b * NN + n0 + lane];
    float mbk = 1.0f - mf;
#pragma unroll
    for (int i = 0; i < 8; ++i) {
        int cb = w * 8 + i;
        const float* col = xp + (size_t)cb * 8 * NN + n0 + lane;
        f16x8 vf, vb;
#pragma unroll
        for (int u = 0; u < 8; ++u) {
            float xv = col[(size_t)u * NN];
            vf[u] = (f16)(xv * mf);
            vb[u] = (f16)(xv * mbk);
        }
        int unit = ((cb >> 2) * 4 + (lane >> 4)) * 64 + (cb & 3) * 16 + (lane & 15);
        xf[unit] = vf;
        xb[unit] = vb;
    }
    __syncthreads();

#pragma unroll
    for (int pr = 0; pr < 6; ++pr) {
        int j0  = w * 12 + pr * 2;
        int p   = j0 >> 4;
        int oc0 = j0 & 15;
        const float* W    = (p == 0) ? Wq : (p == 1) ? Wk : Wv;
        const float* bias = (p == 0) ? bq : (p == 1) ? bk : bv;
        const f16x8* bt   = (p == 0) ? xf : xb;

        f16x8 wf[2][8];
#pragma unroll
        for (int h = 0; h < 2; ++h) {
            const float* wrow = W + (size_t)((oc0 + h) * 16 + l16) * CC + quad * 8;
#pragma unroll
            for (int kc = 0; kc < 8; ++kc) {
                float4 a = *(const float4*)(wrow + kc * 32);
                float4 c = *(const float4*)(wrow + kc * 32 + 4);
                f16x8 f;
                f[0] = (f16)a.x; f[1] = (f16)a.y; f[2] = (f16)a.z; f[3] = (f16)a.w;
                f[4] = (f16)c.x; f[5] = (f16)c.y; f[6] = (f16)c.z; f[7] = (f16)c.w;
                wf[h][kc] = f;
            }
        }
        f32x4 acc[2][4];
#pragma unroll
        for (int h = 0; h < 2; ++h)
#pragma unroll
            for (int nc = 0; nc < 4; ++nc) acc[h][nc] = (f32x4){0.f, 0.f, 0.f, 0.f};
#pragma unroll
        for (int nc = 0; nc < 4; ++nc)
#pragma unroll
            for (int kc = 0; kc < 8; ++kc) {
                f16x8 bf = bt[(kc * 4 + nc) * 64 + lane];
                acc[0][nc] = __builtin_amdgcn_mfma_f32_16x16x32_f16(wf[0][kc], bf, acc[0][nc], 0, 0, 0);
                acc[1][nc] = __builtin_amdgcn_mfma_f32_16x16x32_f16(wf[1][kc], bf, acc[1][nc], 0, 0, 0);
            }
#pragma unroll
        for (int h = 0; h < 2; ++h) {
            int oc = oc0 + h;
            float bvv[4];
#pragma unroll
            for (int r = 0; r < 4; ++r) bvv[r] = bias[oc * 16 + quad * 4 + r];
            if (p == 2) {                        // v [C][N]
                f16* vpl = base + 2 * NM;
#pragma unroll
                for (int nc = 0; nc < 4; ++nc)
#pragma unroll
                    for (int r = 0; r < 4; ++r)
                        vpl[(size_t)(oc * 16 + quad * 4 + r) * NN + n0 + nc * 16 + l16] =
                            (f16)(acc[h][nc][r] + bvv[r]);
            } else {                             // q/k [N][C]
                f16* qpl = base + (size_t)p * NM;
#pragma unroll
                for (int nc = 0; nc < 4; ++nc) {
                    f16x4 pk;
#pragma unroll
                    for (int r = 0; r < 4; ++r) pk[r] = (f16)(acc[h][nc][r] + bvv[r]);
                    *(f16x4*)(qpl + (size_t)(n0 + nc * 16 + l16) * CC + oc * 16 + quad * 4) = pk;
                }
            }
        }
    }
}

// ---------------------------------------------------------------------------
// flash v4: R0 dataflow (64-row block, 4 waves, 16 rows/wave, per-wave
// softmax), serial chain attacked:
//  - m-tile 32, K/V staged via global_load_lds into double-buffered LDS,
//    counted vmcnt(8) + raw s_barrier: loads stay in flight across barriers,
//    no stage-write phase, no prefetch VGPRs.
//  - row-sum L computed by MFMA against a ones-fragment (oacc[16]) with the
//    same alpha rescale -> no shuffle-sum chain, no L bookkeeping.
//  - exact skip-softmax: wave-uniform __any(s>M); when max doesn't grow,
//    skip max-reduce + alpha + rescale entirely (bitwise exact).
//  - s_setprio(1) around MFMA clusters.
// LDS: 2x16K (K) + 2x16K (V) + 5K pbuf = 69 KB -> 2 blocks/CU.
// grid (nb, NN/64) slot-major: K/V reads hit XCD-local L2 (R2: FETCH 25MB).
// ---------------------------------------------------------------------------
__global__ __launch_bounds__(256, 2) void flash_kernel(f16* __restrict__ wsh)
{
    __shared__ f16x8 klds[2][1024];    // 2 x 16 KB : 32m x 256c fragment-major
    __shared__ f16x8 vlds[2][1024];    // 2 x 16 KB : [c][m] fragment-major
    __shared__ f16 pbuf[4][16 * 40];   // 5 KB, per-wave P tile, stride 40

    const int t    = threadIdx.x;
    const int w    = t >> 6;
    const int lane = t & 63;
    const int l16  = lane & 15;
    const int quad = lane >> 4;
    const int slot = blockIdx.x;
    const int n0   = blockIdx.y * 64;

    f16* base = wsh + (size_t)slot * 4 * NM;
    const f16* qt = base;            // [N][C]
    const f16* kt = base + NM;       // [M][C]
    const f16* vp = base + 2 * NM;   // [C][N]
    f16* op       = base + 3 * NM;   // [C][N]

    // staging source offsets: LDS unit u = i*256 + t
    // K unit u holds K[m = ((u>>9)&1)*16 + (u&15)][c = ((u>>6)&7)*32 + ((u>>4)&3)*8 ..+8]
    // V unit u holds V[c = (u>>6)*16 + (u&15)][m = ((u>>4)&3)*8 ..+8]
    int koff[4], voff[4];
#pragma unroll
    for (int i = 0; i < 4; ++i) {
        int u = i * 256 + t;
        koff[i] = (((u >> 9) & 1) * 16 + (u & 15)) * CC
                + ((u >> 6) & 7) * 32 + ((u >> 4) & 3) * 8;
        voff[i] = ((u >> 6) * 16 + (u & 15)) * NN + ((u >> 4) & 3) * 8;
    }

#define ISSUE(m0_, b_) do {                                                     \
    _Pragma("unroll")                                                           \
    for (int i_ = 0; i_ < 4; ++i_)                                              \
        GLD16(kt + (size_t)(m0_) * CC + koff[i_],                               \
              (f16*)&klds[b_][i_ * 256 + w * 64]);                              \
    _Pragma("unroll")                                                           \
    for (int i_ = 0; i_ < 4; ++i_)                                              \
        GLD16(vp + (size_t)(m0_) + voff[i_],                                    \
              (f16*)&vlds[b_][i_ * 256 + w * 64]);                              \
} while (0)

    // Q fragments for this wave's 16 rows
    const int nrow = n0 + w * 16 + l16;
    f16x8 qf[8];
#pragma unroll
    for (int kc = 0; kc < 8; ++kc)
        qf[kc] = *(const f16x8*)(qt + (size_t)nrow * CC + kc * 32 + quad * 8);
    // pin the compiler's qf waitcnt here (pre-loop), before any gld is issued
#pragma unroll
    for (int kc = 0; kc < 8; ++kc)
        asm volatile("" :: "v"(qf[kc]));

    f32x4 oacc[17];                    // [0..15]: O cols; [16]: row-sum L
#pragma unroll
    for (int i = 0; i < 17; ++i) oacc[i] = (f32x4){0.f, 0.f, 0.f, 0.f};
    float M[4] = {-3.0e38f, -3.0e38f, -3.0e38f, -3.0e38f};

    f16* pw = &pbuf[w][0];
    f16x8 ones;
#pragma unroll
    for (int i = 0; i < 8; ++i) ones[i] = (f16)1.0f;

    ISSUE(0, 0);
    int cur = 0;

    for (int it = 0; it < NN / 32; ++it) {
        if (it + 1 < NN / 32) {
            ISSUE((it + 1) * 32, cur ^ 1);
            // drain current tile's 8 loads, keep next tile's 8 in flight
            asm volatile("s_waitcnt vmcnt(8)" ::: "memory");
        } else {
            asm volatile("s_waitcnt vmcnt(0)" ::: "memory");
        }
        __builtin_amdgcn_s_barrier();
        asm volatile("" ::: "memory");

        // ---- QK^T: 16 rows x 32 m ----
        f32x4 s[2];
        s[0] = (f32x4){0.f, 0.f, 0.f, 0.f};
        s[1] = (f32x4){0.f, 0.f, 0.f, 0.f};
        __builtin_amdgcn_s_setprio(1);
#pragma unroll
        for (int kc = 0; kc < 8; ++kc) {
            f16x8 k0 = klds[cur][kc * 64 + lane];
            f16x8 k1 = klds[cur][(8 + kc) * 64 + lane];
            s[0] = __builtin_amdgcn_mfma_f32_16x16x32_f16(qf[kc], k0, s[0], 0, 0, 0);
            s[1] = __builtin_amdgcn_mfma_f32_16x16x32_f16(qf[kc], k1, s[1], 0, 0, 0);
        }
        __builtin_amdgcn_s_setprio(0);

        // ---- softmax with exact skip ----
        bool up = false;
#pragma unroll
        for (int ms = 0; ms < 2; ++ms)
#pragma unroll
            for (int r = 0; r < 4; ++r) up |= (s[ms][r] > M[r]);
        if (__any(up)) {
            float alpha[4];
#pragma unroll
            for (int r = 0; r < 4; ++r) {
                float tm = fmaxf(s[0][r], s[1][r]);
                tm = fmaxf(tm, __shfl_xor(tm, 1, 64));
                tm = fmaxf(tm, __shfl_xor(tm, 2, 64));
                tm = fmaxf(tm, __shfl_xor(tm, 4, 64));
                tm = fmaxf(tm, __shfl_xor(tm, 8, 64));
                float Mn = fmaxf(M[r], tm);
                alpha[r] = __expf(M[r] - Mn);
                M[r] = Mn;
            }
#pragma unroll
            for (int cs = 0; cs < 17; ++cs)
#pragma unroll
                for (int r = 0; r < 4; ++r) oacc[cs][r] *= alpha[r];
        }
        // P = exp(s - M), write per-wave P tile
#pragma unroll
        for (int ms = 0; ms < 2; ++ms)
#pragma unroll
            for (int r = 0; r < 4; ++r)
                pw[(quad * 4 + r) * 40 + ms * 16 + l16] = (f16)__expf(s[ms][r] - M[r]);
        asm volatile("s_waitcnt lgkmcnt(0)" ::: "memory");
        f16x8 pf = *(const f16x8*)(pw + l16 * 40 + quad * 8);

        // ---- PV: 16 rows x 256 c (+ L column) ----
        __builtin_amdgcn_s_setprio(1);
#pragma unroll
        for (int cs = 0; cs < 16; ++cs) {
            f16x8 vf = vlds[cur][cs * 64 + lane];
            oacc[cs] = __builtin_amdgcn_mfma_f32_16x16x32_f16(pf, vf, oacc[cs], 0, 0, 0);
        }
        oacc[16] = __builtin_amdgcn_mfma_f32_16x16x32_f16(pf, ones, oacc[16], 0, 0, 0);
        __builtin_amdgcn_s_setprio(0);

        asm volatile("" ::: "memory");
        __builtin_amdgcn_s_barrier();
        cur ^= 1;
    }

    float inv[4];
#pragma unroll
    for (int r = 0; r < 4; ++r) inv[r] = 1.0f / oacc[16][r];
#pragma unroll
    for (int cs = 0; cs < 16; ++cs)
#pragma unroll
        for (int r = 0; r < 4; ++r)
            op[(size_t)(cs * 16 + l16) * NN + n0 + w * 16 + quad * 4 + r] =
                (f16)(oacc[cs][r] * inv[r]);
#undef ISSUE
}

// ---------------------------------------------------------------------------
// final (MFMA): out[o,n] = Wo·O + bo + gamma*x, fp32 out.
// grid (nb, NN/64) slot-major (O reads hit XCD-local L2).
// ---------------------------------------------------------------------------
__global__ __launch_bounds__(256, 2) void final_kernel(
    const f16* __restrict__ wsh, const float* __restrict__ Wo,
    const float* __restrict__ bo, const float* __restrict__ x,
    const float* __restrict__ gamma, float* __restrict__ outall, int b0)
{
    __shared__ f16x8 ot[2048];   // 32 KB O tile, fragment-major

    const int t = threadIdx.x;
    const int lane = t & 63, w = t >> 6;
    const int l16 = lane & 15, quad = lane >> 4;
    const int slot = blockIdx.x;
    const int b = b0 + slot;
    const int n0 = blockIdx.y * 64;
    const f16* O = wsh + ((size_t)slot * 4 + 3) * NM;
    const float* xp = x + (size_t)b * NM;
    float* outp = outall + (size_t)b * NM;

#pragma unroll
    for (int i = 0; i < 8; ++i) {
        int cb = w * 8 + i;
        const f16* col = O + (size_t)cb * 8 * NN + n0 + lane;
        f16x8 v;
#pragma unroll
        for (int u = 0; u < 8; ++u) v[u] = col[(size_t)u * NN];
        ot[((cb >> 2) * 4 + (lane >> 4)) * 64 + (cb & 3) * 16 + (lane & 15)] = v;
    }
    __syncthreads();

    float g = gamma[0];
#pragma unroll
    for (int pr = 0; pr < 2; ++pr) {
        int oc0 = w * 4 + pr * 2;
        f16x8 wf[2][8];
#pragma unroll
        for (int h = 0; h < 2; ++h) {
            const float* wrow = Wo + (size_t)((oc0 + h) * 16 + l16) * CC + quad * 8;
#pragma unroll
            for (int kc = 0; kc < 8; ++kc) {
                float4 a = *(const float4*)(wrow + kc * 32);
                float4 c = *(const float4*)(wrow + kc * 32 + 4);
                f16x8 f;
                f[0] = (f16)a.x; f[1] = (f16)a.y; f[2] = (f16)a.z; f[3] = (f16)a.w;
                f[4] = (f16)c.x; f[5] = (f16)c.y; f[6] = (f16)c.z; f[7] = (f16)c.w;
                wf[h][kc] = f;
            }
        }
        f32x4 acc[2][4];
#pragma unroll
        for (int h = 0; h < 2; ++h)
#pragma unroll
            for (int nc = 0; nc < 4; ++nc) acc[h][nc] = (f32x4){0.f, 0.f, 0.f, 0.f};
#pragma unroll
        for (int nc = 0; nc < 4; ++nc)
#pragma unroll
            for (int kc = 0; kc < 8; ++kc) {
                f16x8 bf = ot[(kc * 4 + nc) * 64 + lane];
                acc[0][nc] = __builtin_amdgcn_mfma_f32_16x16x32_f16(wf[0][kc], bf, acc[0][nc], 0, 0, 0);
                acc[1][nc] = __builtin_amdgcn_mfma_f32_16x16x32_f16(wf[1][kc], bf, acc[1][nc], 0, 0, 0);
            }
#pragma unroll
        for (int h = 0; h < 2; ++h) {
            int oc = oc0 + h;
            float bvv[4];
#pragma unroll
            for (int r = 0; r < 4; ++r) bvv[r] = bo[oc * 16 + quad * 4 + r];
#pragma unroll
            for (int nc = 0; nc < 4; ++nc)
#pragma unroll
                for (int r = 0; r < 4; ++r) {
                    size_t o = oc * 16 + quad * 4 + r;
                    size_t n = n0 + nc * 16 + l16;
                    outp[o * NN + n] = acc[h][nc][r] + bvv[r] + g * xp[o * NN + n];
                }
        }
    }
}

// ---------------------------------------------------------------------------
__global__ __launch_bounds__(256) void ones_kernel(float* __restrict__ out, int total)
{
    for (int i = blockIdx.x * 256 + threadIdx.x; i < total; i += gridDim.x * 256)
        out[i] = 1.0f;
}

// ---------------------------------------------------------------------------
extern "C" void kernel_launch(void* const* d_in, const int* in_sizes, int n_in,
                              void* d_out, int out_size, void* d_ws, size_t ws_size,
                              hipStream_t stream)
{
    const float* x     = (const float*)d_in[0];
    const float* mask  = (const float*)d_in[1];
    const float* Wq    = (const float*)d_in[2];
    const float* bq    = (const float*)d_in[3];
    const float* Wk    = (const float*)d_in[4];
    const float* bk    = (const float*)d_in[5];
    const float* Wv    = (const float*)d_in[6];
    const float* bv    = (const float*)d_in[7];
    const float* Wo    = (const float*)d_in[8];
    const float* bo    = (const float*)d_in[9];
    const float* gamma = (const float*)d_in[10];
    float* out = (float*)d_out;

    const size_t slot_bytes = 4 * NM * sizeof(f16);   // 8 MiB
    f16* wsh = (f16*)d_ws;
    int nb = (int)(ws_size / slot_bytes);
    if (nb < 1) {
        ones_kernel<<<2048, 256, 0, stream>>>(out, out_size);
        return;
    }
    if (nb > NB) nb = NB;

    for (int b0 = 0; b0 < NB; b0 += nb) {
        int nbc = NB - b0; if (nbc > nb) nbc = nb;
        dim3 gT(nbc, NN / 64);   // slot-major: slot -> XCD (L2 affinity)
        proj_fused_kernel<<<gT, 256, 0, stream>>>(x, mask, Wq, bq, Wk, bk, Wv, bv, wsh, b0);
        flash_kernel<<<gT, 256, 0, stream>>>(wsh);
        final_kernel<<<gT, 256, 0, stream>>>(wsh, Wo, bo, x, gamma, out, b0);
    }
}

// Round 7
// 336.278 us; speedup vs baseline: 1.5773x; 1.3206x over previous
//
#include <hip/hip_runtime.h>

#define CC 256
#define NN 4096
#define NB 8
#define NM ((size_t)CC * NN)   // 1M elems per plane

typedef _Float16 f16;
typedef f16 f16x4 __attribute__((ext_vector_type(4)));
typedef f16 f16x8 __attribute__((ext_vector_type(8)));
typedef float f32x4 __attribute__((ext_vector_type(4)));
typedef unsigned int u32;

// async global->LDS, 16 B per lane; LDS dest = wave-uniform base + lane*16
#define GLD16(gp, lp) __builtin_amdgcn_global_load_lds( \
    (const __attribute__((address_space(1))) u32*)(const void*)(gp), \
    (__attribute__((address_space(3))) u32*)(void*)(lp), 16, 0, 0)

// ---------------------------------------------------------------------------
// mask_scan: per batch, exclusive prefix-sum over (mask==0) -> compacted
// background column index posm[n] (or -1 for foreground), and counts[b] = F_b.
// Key fact: mask is exactly 0/1, so foreground k/v columns are exactly bk/bv
// -> they collapse to ONE analytic softmax column (handled in flash epilogue).
// posm/counts live in the tail of d_out (final_kernel overwrites it last).
// ---------------------------------------------------------------------------
__global__ __launch_bounds__(256) void mask_scan_kernel(
    const float* __restrict__ mask, int* __restrict__ posm, int* __restrict__ counts)
{
    const int b = blockIdx.x;
    const int t = threadIdx.x;
    const int lane = t & 63, w = t >> 6;
    __shared__ int wsum[4];
    const float* mp = mask + (size_t)b * NN;
    int* pp = posm + (size_t)b * NN;

    int loc[16], cnt = 0;
#pragma unroll
    for (int i = 0; i < 16; ++i) {
        loc[i] = cnt;
        cnt += (mp[t * 16 + i] == 0.0f) ? 1 : 0;
    }
    int inc = cnt;                         // inclusive scan over 64 lanes
#pragma unroll
    for (int d = 1; d < 64; d <<= 1) {
        int v = __shfl_up(inc, d, 64);
        if (lane >= d) inc += v;
    }
    if (lane == 63) wsum[w] = inc;
    int exc = inc - cnt;
    __syncthreads();
    int base = exc;
    for (int i = 0; i < w; ++i) base += wsum[i];
#pragma unroll
    for (int i = 0; i < 16; ++i)
        pp[t * 16 + i] = (mp[t * 16 + i] == 0.0f) ? (base + loc[i]) : -1;
    if (t == 0) counts[b] = wsum[0] + wsum[1] + wsum[2] + wsum[3];
}

// ---------------------------------------------------------------------------
// proj_fused: q = Wq(x*m)+bq (all n), k/v = projections of x*(1-m) written
// COMPACTED: k row / v column -> posm[n] (foreground skipped; those columns
// are exactly bk/bv and handled analytically in flash). blockIdx.y==0 blocks
// zero the <=31-row/col pad beyond F_b so no garbage reaches QK^T/PV.
// grid (nb, NN/64) slot-major (XCD L2 affinity, R2/R3: FETCH 139->25 MB).
// ---------------------------------------------------------------------------
__global__ __launch_bounds__(256, 2) void proj_fused_kernel(
    const float* __restrict__ x, const float* __restrict__ mask,
    const float* __restrict__ Wq, const float* __restrict__ bq,
    const float* __restrict__ Wk, const float* __restrict__ bk,
    const float* __restrict__ Wv, const float* __restrict__ bv,
    f16* __restrict__ wsh, const int* __restrict__ posm,
    const int* __restrict__ counts, int b0)
{
    __shared__ f16x8 xf[2048];   // 32 KB, (x*m) fragment-major
    __shared__ f16x8 xb[2048];   // 32 KB, (x*(1-m))

    const int t = threadIdx.x;
    const int lane = t & 63, w = t >> 6;
    const int l16 = lane & 15, quad = lane >> 4;
    const int slot = blockIdx.x;
    const int b = b0 + slot;
    const int n0 = blockIdx.y * 64;
    const float* xp = x + (size_t)b * NM;
    f16* base = wsh + (size_t)slot * 4 * NM;
    const int* pom = posm + (size_t)b * NN;

    float mf  = mask[(size_t)b * NN + n0 + lane];
    float mbk = 1.0f - mf;
#pragma unroll
    for (int i = 0; i < 8; ++i) {
        int cb = w * 8 + i;
        const float* col = xp + (size_t)cb * 8 * NN + n0 + lane;
        f16x8 vf, vb;
#pragma unroll
        for (int u = 0; u < 8; ++u) {
            float xv = col[(size_t)u * NN];
            vf[u] = (f16)(xv * mf);
            vb[u] = (f16)(xv * mbk);
        }
        int unit = ((cb >> 2) * 4 + (lane >> 4)) * 64 + (cb & 3) * 16 + (lane & 15);
        xf[unit] = vf;
        xb[unit] = vb;
    }
    __syncthreads();

#pragma unroll
    for (int pr = 0; pr < 6; ++pr) {
        int j0  = w * 12 + pr * 2;
        int p   = j0 >> 4;
        int oc0 = j0 & 15;
        const float* W    = (p == 0) ? Wq : (p == 1) ? Wk : Wv;
        const float* bias = (p == 0) ? bq : (p == 1) ? bk : bv;
        const f16x8* bt   = (p == 0) ? xf : xb;

        f16x8 wf[2][8];
#pragma unroll
        for (int h = 0; h < 2; ++h) {
            const float* wrow = W + (size_t)((oc0 + h) * 16 + l16) * CC + quad * 8;
#pragma unroll
            for (int kc = 0; kc < 8; ++kc) {
                float4 a = *(const float4*)(wrow + kc * 32);
                float4 c = *(const float4*)(wrow + kc * 32 + 4);
                f16x8 f;
                f[0] = (f16)a.x; f[1] = (f16)a.y; f[2] = (f16)a.z; f[3] = (f16)a.w;
                f[4] = (f16)c.x; f[5] = (f16)c.y; f[6] = (f16)c.z; f[7] = (f16)c.w;
                wf[h][kc] = f;
            }
        }
        f32x4 acc[2][4];
#pragma unroll
        for (int h = 0; h < 2; ++h)
#pragma unroll
            for (int nc = 0; nc < 4; ++nc) acc[h][nc] = (f32x4){0.f, 0.f, 0.f, 0.f};
#pragma unroll
        for (int nc = 0; nc < 4; ++nc)
#pragma unroll
            for (int kc = 0; kc < 8; ++kc) {
                f16x8 bf = bt[(kc * 4 + nc) * 64 + lane];
                acc[0][nc] = __builtin_amdgcn_mfma_f32_16x16x32_f16(wf[0][kc], bf, acc[0][nc], 0, 0, 0);
                acc[1][nc] = __builtin_amdgcn_mfma_f32_16x16x32_f16(wf[1][kc], bf, acc[1][nc], 0, 0, 0);
            }
#pragma unroll
        for (int h = 0; h < 2; ++h) {
            int oc = oc0 + h;
            float bvv[4];
#pragma unroll
            for (int r = 0; r < 4; ++r) bvv[r] = bias[oc * 16 + quad * 4 + r];
            if (p == 2) {                        // v [C][M] column-scatter
                f16* vpl = base + 2 * NM;
#pragma unroll
                for (int nc = 0; nc < 4; ++nc) {
                    int cp = pom[n0 + nc * 16 + l16];
                    if (cp >= 0) {
#pragma unroll
                        for (int r = 0; r < 4; ++r)
                            vpl[(size_t)(oc * 16 + quad * 4 + r) * NN + cp] =
                                (f16)(acc[h][nc][r] + bvv[r]);
                    }
                }
            } else if (p == 1) {                 // k [M][C] row-scatter
                f16* kpl = base + NM;
#pragma unroll
                for (int nc = 0; nc < 4; ++nc) {
                    int cp = pom[n0 + nc * 16 + l16];
                    if (cp >= 0) {
                        f16x4 pk;
#pragma unroll
                        for (int r = 0; r < 4; ++r) pk[r] = (f16)(acc[h][nc][r] + bvv[r]);
                        *(f16x4*)(kpl + (size_t)cp * CC + oc * 16 + quad * 4) = pk;
                    }
                }
            } else {                             // q [N][C], all rows
                f16* qpl = base;
#pragma unroll
                for (int nc = 0; nc < 4; ++nc) {
                    f16x4 pk;
#pragma unroll
                    for (int r = 0; r < 4; ++r) pk[r] = (f16)(acc[h][nc][r] + bvv[r]);
                    *(f16x4*)(qpl + (size_t)(n0 + nc * 16 + l16) * CC + oc * 16 + quad * 4) = pk;
                }
            }
        }
    }

    // zero the compaction pad (rows/cols F_b .. ceil32(F_b)) once per slot
    if (blockIdx.y == 0) {
        int Fb = counts[b];
        int Mp = (Fb + 31) & ~31;
        int pad = Mp - Fb;
        if (pad > 0) {
            f16* kpl = base + NM;
            f16* vpl = base + 2 * NM;
            f16x8 z8;
#pragma unroll
            for (int i = 0; i < 8; ++i) z8[i] = (f16)0.0f;
            for (int idx = t; idx < pad * 32; idx += 256)   // k: pad rows x 256 c
                *(f16x8*)(kpl + (size_t)(Fb + idx / 32) * CC + (idx & 31) * 8) = z8;
            for (int idx = t; idx < pad * CC; idx += 256)   // v: 256 c x pad cols
                vpl[(size_t)(idx / pad) * NN + Fb + (idx % pad)] = (f16)0.0f;
        }
    }
}

// ---------------------------------------------------------------------------
// flash v6 = verified R3 structure (16x16x32, 64-row block, 4 waves, per-wave
// softmax, GLD16 double-buffer, counted vmcnt(8), MFMA ones-column L) with:
//  - m-loop over COMPACTED background columns only: nt = ceil(F_b/32) tiles
//    (~half of NN/32), loop bound from counts[].
//  - last-tile masking: s = -3e38 for m >= F_b (exact zero weight).
//  - epilogue: analytic foreground column -- score cn = q_row . bk (fp32),
//    weight F_f = NN - F_b, value bv: standard online-softmax update of
//    (oacc, L-column) by one more column with multiplicity F_f. Exact algebra.
// ---------------------------------------------------------------------------
__global__ __launch_bounds__(256, 2) void flash_kernel(
    f16* __restrict__ wsh, const float* __restrict__ bk,
    const float* __restrict__ bv, const int* __restrict__ counts, int b0)
{
    __shared__ f16x8 klds[2][1024];    // 2 x 16 KB : 32m x 256c fragment-major
    __shared__ f16x8 vlds[2][1024];    // 2 x 16 KB : [c][m] fragment-major
    __shared__ f16 pbuf[4][16 * 40];   // 5 KB, per-wave P tile, stride 40

    const int t    = threadIdx.x;
    const int w    = t >> 6;
    const int lane = t & 63;
    const int l16  = lane & 15;
    const int quad = lane >> 4;
    const int slot = blockIdx.x;
    const int n0   = blockIdx.y * 64;

    f16* base = wsh + (size_t)slot * 4 * NM;
    const f16* qt = base;            // [N][C]
    const f16* kt = base + NM;       // [M][C] compacted
    const f16* vp = base + 2 * NM;   // [C][M] compacted
    f16* op       = base + 3 * NM;   // [C][N]

    const int Fb = counts[b0 + slot];
    const int nt = (Fb + 31) >> 5;

    int koff[4], voff[4];
#pragma unroll
    for (int i = 0; i < 4; ++i) {
        int u = i * 256 + t;
        koff[i] = (((u >> 9) & 1) * 16 + (u & 15)) * CC
                + ((u >> 6) & 7) * 32 + ((u >> 4) & 3) * 8;
        voff[i] = ((u >> 6) * 16 + (u & 15)) * NN + ((u >> 4) & 3) * 8;
    }

#define ISSUE(m0_, b_) do {                                                     \
    _Pragma("unroll")                                                           \
    for (int i_ = 0; i_ < 4; ++i_)                                              \
        GLD16(kt + (size_t)(m0_) * CC + koff[i_],                               \
              (f16*)&klds[b_][i_ * 256 + w * 64]);                              \
    _Pragma("unroll")                                                           \
    for (int i_ = 0; i_ < 4; ++i_)                                              \
        GLD16(vp + (size_t)(m0_) + voff[i_],                                    \
              (f16*)&vlds[b_][i_ * 256 + w * 64]);                              \
} while (0)

    // Q fragments for this wave's 16 rows
    const int nrow = n0 + w * 16 + l16;
    f16x8 qf[8];
#pragma unroll
    for (int kc = 0; kc < 8; ++kc)
        qf[kc] = *(const f16x8*)(qt + (size_t)nrow * CC + kc * 32 + quad * 8);
#pragma unroll
    for (int kc = 0; kc < 8; ++kc)
        asm volatile("" :: "v"(qf[kc]));
    // drain all prior VMEM so staging is the only thing vmcnt counts
    asm volatile("s_waitcnt vmcnt(0)" ::: "memory");

    f32x4 oacc[17];                    // [0..15]: O cols; [16]: row-sum L
#pragma unroll
    for (int i = 0; i < 17; ++i) oacc[i] = (f32x4){0.f, 0.f, 0.f, 0.f};
    float M[4] = {-3.0e38f, -3.0e38f, -3.0e38f, -3.0e38f};

    f16* pw = &pbuf[w][0];
    f16x8 ones;
#pragma unroll
    for (int i = 0; i < 8; ++i) ones[i] = (f16)1.0f;

    if (nt > 0) ISSUE(0, 0);
    int cur = 0;

    for (int it = 0; it < nt; ++it) {
        if (it + 1 < nt) {
            ISSUE((it + 1) * 32, cur ^ 1);
            asm volatile("s_waitcnt vmcnt(8)" ::: "memory");
        } else {
            asm volatile("s_waitcnt vmcnt(0)" ::: "memory");
        }
        __builtin_amdgcn_s_barrier();
        asm volatile("" ::: "memory");

        // ---- QK^T: 16 rows x 32 m ----
        f32x4 s[2];
        s[0] = (f32x4){0.f, 0.f, 0.f, 0.f};
        s[1] = (f32x4){0.f, 0.f, 0.f, 0.f};
        __builtin_amdgcn_s_setprio(1);
#pragma unroll
        for (int kc = 0; kc < 8; ++kc) {
            f16x8 k0 = klds[cur][kc * 64 + lane];
            f16x8 k1 = klds[cur][(8 + kc) * 64 + lane];
            s[0] = __builtin_amdgcn_mfma_f32_16x16x32_f16(qf[kc], k0, s[0], 0, 0, 0);
            s[1] = __builtin_amdgcn_mfma_f32_16x16x32_f16(qf[kc], k1, s[1], 0, 0, 0);
        }
        __builtin_amdgcn_s_setprio(0);

        // ---- tail mask: columns beyond F_b get exactly zero weight ----
        if (((it + 1) << 5) > Fb) {
#pragma unroll
            for (int ms = 0; ms < 2; ++ms)
                if (it * 32 + ms * 16 + l16 >= Fb) {
#pragma unroll
                    for (int r = 0; r < 4; ++r) s[ms][r] = -3.0e38f;
                }
        }

        // ---- softmax with exact skip ----
        bool up = false;
#pragma unroll
        for (int ms = 0; ms < 2; ++ms)
#pragma unroll
            for (int r = 0; r < 4; ++r) up |= (s[ms][r] > M[r]);
        if (__any(up)) {
            float alpha[4];
#pragma unroll
            for (int r = 0; r < 4; ++r) {
                float tm = fmaxf(s[0][r], s[1][r]);
                tm = fmaxf(tm, __shfl_xor(tm, 1, 64));
                tm = fmaxf(tm, __shfl_xor(tm, 2, 64));
                tm = fmaxf(tm, __shfl_xor(tm, 4, 64));
                tm = fmaxf(tm, __shfl_xor(tm, 8, 64));
                float Mn = fmaxf(M[r], tm);
                alpha[r] = __expf(M[r] - Mn);
                M[r] = Mn;
            }
#pragma unroll
            for (int cs = 0; cs < 17; ++cs)
#pragma unroll
                for (int r = 0; r < 4; ++r) oacc[cs][r] *= alpha[r];
        }
        // P = exp(s - M), write per-wave P tile
#pragma unroll
        for (int ms = 0; ms < 2; ++ms)
#pragma unroll
            for (int r = 0; r < 4; ++r)
                pw[(quad * 4 + r) * 40 + ms * 16 + l16] = (f16)__expf(s[ms][r] - M[r]);
        asm volatile("s_waitcnt lgkmcnt(0)" ::: "memory");
        f16x8 pf = *(const f16x8*)(pw + l16 * 40 + quad * 8);

        // ---- PV: 16 rows x 256 c (+ L column) ----
        __builtin_amdgcn_s_setprio(1);
#pragma unroll
        for (int cs = 0; cs < 16; ++cs) {
            f16x8 vf = vlds[cur][cs * 64 + lane];
            oacc[cs] = __builtin_amdgcn_mfma_f32_16x16x32_f16(pf, vf, oacc[cs], 0, 0, 0);
        }
        oacc[16] = __builtin_amdgcn_mfma_f32_16x16x32_f16(pf, ones, oacc[16], 0, 0, 0);
        __builtin_amdgcn_s_setprio(0);

        asm volatile("" ::: "memory");
        __builtin_amdgcn_s_barrier();
        cur ^= 1;
    }
    asm volatile("s_waitcnt vmcnt(0)" ::: "memory");  // nt==0 safety / leftovers

    // ---- analytic foreground column: score q.bk, weight F_f, value bv ----
    {
        float cn = 0.f;
#pragma unroll
        for (int kc = 0; kc < 8; ++kc) {
            const float* bkp = bk + kc * 32 + quad * 8;
#pragma unroll
            for (int j = 0; j < 8; ++j)
                cn += (float)qf[kc][j] * bkp[j];
        }
        cn += __shfl_xor(cn, 16, 64);   // lanes with same l16 now hold full dot
        cn += __shfl_xor(cn, 32, 64);
        const float Ff = (float)(NN - Fb);
        float aw[4], wv[4];
#pragma unroll
        for (int r = 0; r < 4; ++r) {
            float cr = __shfl(cn, quad * 4 + r, 64);   // row quad*4+r's score
            float Mn = fmaxf(M[r], cr);
            aw[r] = __expf(M[r] - Mn);
            wv[r] = Ff * __expf(cr - Mn);
            M[r] = Mn;
        }
#pragma unroll
        for (int cs = 0; cs < 16; ++cs) {
            float bvc = bv[cs * 16 + l16];
#pragma unroll
            for (int r = 0; r < 4; ++r)
                oacc[cs][r] = oacc[cs][r] * aw[r] + wv[r] * bvc;
        }
#pragma unroll
        for (int r = 0; r < 4; ++r)
            oacc[16][r] = oacc[16][r] * aw[r] + wv[r];
    }

    float inv[4];
#pragma unroll
    for (int r = 0; r < 4; ++r) inv[r] = 1.0f / oacc[16][r];
#pragma unroll
    for (int cs = 0; cs < 16; ++cs)
#pragma unroll
        for (int r = 0; r < 4; ++r)
            op[(size_t)(cs * 16 + l16) * NN + n0 + w * 16 + quad * 4 + r] =
                (f16)(oacc[cs][r] * inv[r]);
#undef ISSUE
}

// ---------------------------------------------------------------------------
// final (MFMA): out[o,n] = Wo·O + bo + gamma*x, fp32 out. (unchanged R3)
// ---------------------------------------------------------------------------
__global__ __launch_bounds__(256, 2) void final_kernel(
    const f16* __restrict__ wsh, const float* __restrict__ Wo,
    const float* __restrict__ bo, const float* __restrict__ x,
    const float* __restrict__ gamma, float* __restrict__ outall, int b0)
{
    __shared__ f16x8 ot[2048];   // 32 KB O tile, fragment-major

    const int t = threadIdx.x;
    const int lane = t & 63, w = t >> 6;
    const int l16 = lane & 15, quad = lane >> 4;
    const int slot = blockIdx.x;
    const int b = b0 + slot;
    const int n0 = blockIdx.y * 64;
    const f16* O = wsh + ((size_t)slot * 4 + 3) * NM;
    const float* xp = x + (size_t)b * NM;
    float* outp = outall + (size_t)b * NM;

#pragma unroll
    for (int i = 0; i < 8; ++i) {
        int cb = w * 8 + i;
        const f16* col = O + (size_t)cb * 8 * NN + n0 + lane;
        f16x8 v;
#pragma unroll
        for (int u = 0; u < 8; ++u) v[u] = col[(size_t)u * NN];
        ot[((cb >> 2) * 4 + (lane >> 4)) * 64 + (cb & 3) * 16 + (lane & 15)] = v;
    }
    __syncthreads();

    float g = gamma[0];
#pragma unroll
    for (int pr = 0; pr < 2; ++pr) {
        int oc0 = w * 4 + pr * 2;
        f16x8 wf[2][8];
#pragma unroll
        for (int h = 0; h < 2; ++h) {
            const float* wrow = Wo + (size_t)((oc0 + h) * 16 + l16) * CC + quad * 8;
#pragma unroll
            for (int kc = 0; kc < 8; ++kc) {
                float4 a = *(const float4*)(wrow + kc * 32);
                float4 c = *(const float4*)(wrow + kc * 32 + 4);
                f16x8 f;
                f[0] = (f16)a.x; f[1] = (f16)a.y; f[2] = (f16)a.z; f[3] = (f16)a.w;
                f[4] = (f16)c.x; f[5] = (f16)c.y; f[6] = (f16)c.z; f[7] = (f16)c.w;
                wf[h][kc] = f;
            }
        }
        f32x4 acc[2][4];
#pragma unroll
        for (int h = 0; h < 2; ++h)
#pragma unroll
            for (int nc = 0; nc < 4; ++nc) acc[h][nc] = (f32x4){0.f, 0.f, 0.f, 0.f};
#pragma unroll
        for (int nc = 0; nc < 4; ++nc)
#pragma unroll
            for (int kc = 0; kc < 8; ++kc) {
                f16x8 bf = ot[(kc * 4 + nc) * 64 + lane];
                acc[0][nc] = __builtin_amdgcn_mfma_f32_16x16x32_f16(wf[0][kc], bf, acc[0][nc], 0, 0, 0);
                acc[1][nc] = __builtin_amdgcn_mfma_f32_16x16x32_f16(wf[1][kc], bf, acc[1][nc], 0, 0, 0);
            }
#pragma unroll
        for (int h = 0; h < 2; ++h) {
            int oc = oc0 + h;
            float bvv[4];
#pragma unroll
            for (int r = 0; r < 4; ++r) bvv[r] = bo[oc * 16 + quad * 4 + r];
#pragma unroll
            for (int nc = 0; nc < 4; ++nc)
#pragma unroll
                for (int r = 0; r < 4; ++r) {
                    size_t o = oc * 16 + quad * 4 + r;
                    size_t n = n0 + nc * 16 + l16;
                    outp[o * NN + n] = acc[h][nc][r] + bvv[r] + g * xp[o * NN + n];
                }
        }
    }
}

// ---------------------------------------------------------------------------
__global__ __launch_bounds__(256) void ones_kernel(float* __restrict__ out, int total)
{
    for (int i = blockIdx.x * 256 + threadIdx.x; i < total; i += gridDim.x * 256)
        out[i] = 1.0f;
}

// ---------------------------------------------------------------------------
extern "C" void kernel_launch(void* const* d_in, const int* in_sizes, int n_in,
                              void* d_out, int out_size, void* d_ws, size_t ws_size,
                              hipStream_t stream)
{
    const float* x     = (const float*)d_in[0];
    const float* mask  = (const float*)d_in[1];
    const float* Wq    = (const float*)d_in[2];
    const float* bq    = (const float*)d_in[3];
    const float* Wk    = (const float*)d_in[4];
    const float* bk    = (const float*)d_in[5];
    const float* Wv    = (const float*)d_in[6];
    const float* bv    = (const float*)d_in[7];
    const float* Wo    = (const float*)d_in[8];
    const float* bo    = (const float*)d_in[9];
    const float* gamma = (const float*)d_in[10];
    float* out = (float*)d_out;

    const size_t slot_bytes = 4 * NM * sizeof(f16);   // 8 MiB
    f16* wsh = (f16*)d_ws;
    int nb = (int)(ws_size / slot_bytes);
    if (nb < 1) {
        ones_kernel<<<2048, 256, 0, stream>>>(out, out_size);
        return;
    }
    if (nb > NB) nb = NB;

    // posm/counts scratch in the tail of d_out (final_kernel overwrites last)
    int* scratch = (int*)out + ((size_t)out_size - (size_t)(NB * NN + 64));
    int* posm   = scratch;
    int* counts = scratch + NB * NN;
    mask_scan_kernel<<<NB, 256, 0, stream>>>(mask, posm, counts);

    for (int b0 = 0; b0 < NB; b0 += nb) {
        int nbc = NB - b0; if (nbc > nb) nbc = nb;
        dim3 gT(nbc, NN / 64);   // slot-major: slot -> XCD (L2 affinity)
        proj_fused_kernel<<<gT, 256, 0, stream>>>(x, mask, Wq, bq, Wk, bk, Wv, bv,
                                                  wsh, posm, counts, b0);
        flash_kernel<<<gT, 256, 0, stream>>>(wsh, bk, bv, counts, b0);
        final_kernel<<<gT, 256, 0, stream>>>(wsh, Wo, bo, x, gamma, out, b0);
    }
}